// Round 8
// baseline (201.483 us; speedup 1.0000x reference)
//
#include <hip/hip_runtime.h>
#include <hip/hip_bf16.h>
#include <math.h>

// Problem constants
#define S_LEN   2048
#define BATCH   2
#define DMODEL  1024
#define NHEADS  16
#define DKH     64
#define MROWS   (BATCH * S_LEN)   // 4096

// attn R20 geometry: q-tile = 32 rows (qt 0..63), KVBLK = 32 tiles.
// Block = 2 waves, SAME 32 q-rows, KV chunk split between waves (LDS combine).
// qt 0..33: single block (chunk = qt+1 <= 34 tiles, <=17 per wave).
// qt 34..63: two blocks: spl0 = tiles [0,34), spl1 = [34, qt+1); each block
// writes a 32-row fp32 partial slot; attn_combine sums pairs.
// Slots: 32 bh x 30 qt x 2 = 1920 x (32x64 o + 32 l) fp32 = 15.97MB in d_out.
#define QT_SPLIT   34
#define NPIECE_Y   94              // 60 split pieces + 34 singles
#define PO2_FLOATS (1920 * 2048)   // o partials; l partials appended after

typedef __attribute__((ext_vector_type(8)))  __bf16 bf16x8;
typedef __attribute__((ext_vector_type(4)))  float  f32x4;
typedef __attribute__((ext_vector_type(16))) float  f32x16;
typedef __attribute__((ext_vector_type(8)))  unsigned short u16x8;

__device__ __forceinline__ float bfu2f(unsigned short u) {
    union { unsigned int i; float f; } v;
    v.i = ((unsigned int)u) << 16;
    return v.f;
}

__device__ __forceinline__ unsigned short f2bfu(float f) {
    union { __bf16 h; unsigned short u; } v;
    v.h = (__bf16)f;    // native RNE cvt
    return v.u;
}

#define LGKM0() __builtin_amdgcn_s_waitcnt(0xc07f)   // lgkmcnt(0), vmcnt free

// counted-vmcnt + raw barrier (T4)
#define VMCNT_BAR(n) do {                                        \
    asm volatile("s_waitcnt vmcnt(" #n ")" ::: "memory");        \
    __builtin_amdgcn_s_barrier();                                \
    __builtin_amdgcn_sched_barrier(0);                           \
} while (0)

// global -> LDS direct DMA, 16B per lane
__device__ __forceinline__ void gload_lds16(const void* g, void* l) {
    __builtin_amdgcn_global_load_lds(
        (const __attribute__((address_space(1))) void*)g,
        (__attribute__((address_space(3))) void*)l, 16, 0, 0);
}

// ---------------------------------------------------------------------------
// Pre-convert kernels (unchanged).
// ---------------------------------------------------------------------------
__global__ __launch_bounds__(256) void cvt_all(
    const float* __restrict__ W0, const float* __restrict__ W1, const float* __restrict__ W2,
    const float* __restrict__ X,
    unsigned short* __restrict__ Wb, unsigned short* __restrict__ Xb)
{
    const int y = blockIdx.y;
    const float* src;
    unsigned short* dst;
    if (y < 3) {
        src = (y == 0) ? W0 : (y == 1) ? W1 : W2;
        dst = Wb + (size_t)y * (DMODEL * DMODEL);
    } else {
        src = X + (size_t)(y - 3) * (DMODEL * DMODEL);
        dst = Xb + (size_t)(y - 3) * (DMODEL * DMODEL);
    }
    size_t idx = ((size_t)blockIdx.x * 256 + threadIdx.x) * 8;
    float4 a = *(const float4*)(src + idx);
    float4 b = *(const float4*)(src + idx + 4);
    u16x8 h;
    h[0] = f2bfu(a.x); h[1] = f2bfu(a.y); h[2] = f2bfu(a.z); h[3] = f2bfu(a.w);
    h[4] = f2bfu(b.x); h[5] = f2bfu(b.y); h[6] = f2bfu(b.z); h[7] = f2bfu(b.w);
    *(u16x8*)(dst + idx) = h;
}

__global__ __launch_bounds__(256) void cvt_wo(
    const float* __restrict__ W, unsigned short* __restrict__ Wob)
{
    size_t idx = ((size_t)blockIdx.x * 256 + threadIdx.x) * 8;
    float4 a = *(const float4*)(W + idx);
    float4 b = *(const float4*)(W + idx + 4);
    u16x8 h;
    h[0] = f2bfu(a.x); h[1] = f2bfu(a.y); h[2] = f2bfu(a.z); h[3] = f2bfu(a.w);
    h[4] = f2bfu(b.x); h[5] = f2bfu(b.y); h[6] = f2bfu(b.z); h[7] = f2bfu(b.w);
    *(u16x8*)(Wob + idx) = h;
}

// ---------------------------------------------------------------------------
// QKV MFMA GEMM (R16, measured-best): 3-buffer counted-vmcnt. Unchanged.
// ---------------------------------------------------------------------------
__global__ __launch_bounds__(256) void gemm_qkv(
    const unsigned short* __restrict__ Xb,
    const unsigned short* __restrict__ Wb,
    unsigned short* __restrict__ Yq, unsigned short* __restrict__ Yk, unsigned short* __restrict__ Yv)
{
    __shared__ __align__(16) unsigned char pool[49152];
    unsigned short* base = (unsigned short*)pool;

    const int tid  = threadIdx.x;
    const int wave = tid >> 6;
    const int lane = tid & 63;
    const int c    = lane & 15;
    const int quad = lane >> 4;

    const int m0 = blockIdx.y * 128;
    const int n0 = blockIdx.x * 128;
    const int w_idx = n0 >> 10;
    const int e0    = n0 & 1023;
    const unsigned short* Wsrc = Wb + (size_t)w_idx * (DMODEL * DMODEL);

    const int mhalf = (wave & 1) * 64;
    const int nhalf = (wave >> 1) * 64;

    f32x4 acc[4][4];
#pragma unroll
    for (int i = 0; i < 4; i++)
#pragma unroll
        for (int j = 0; j < 4; j++) acc[i][j] = (f32x4){0.f, 0.f, 0.f, 0.f};

    const int srow = wave * 32 + (lane >> 2);
    const int scol = (lane & 3) * 8;
    const unsigned short* Asrc = Xb   + (size_t)(m0 + srow) * DMODEL + scol;
    const unsigned short* Bsrc = Wsrc + (size_t)(e0 + srow) * DMODEL + scol;
    const int doff = srow * 32 + scol;

#define QKV_STAGE(buf, kt) do {                                                    \
    unsigned short* _A = base + (buf) * 8192;                                      \
    unsigned short* _B = _A + 4096;                                                \
    const int _k0 = (kt) * 32;                                                     \
    _Pragma("unroll")                                                              \
    for (int _j = 0; _j < 2; _j++) {                                               \
        gload_lds16(Asrc + (size_t)(_j * 16) * DMODEL + _k0, _A + doff + _j * 512);\
        gload_lds16(Bsrc + (size_t)(_j * 16) * DMODEL + _k0, _B + doff + _j * 512);\
    }                                                                              \
} while (0)

#define QKV_COMPUTE(buf) do {                                                      \
    const unsigned short* _A = base + (buf) * 8192;                                \
    const unsigned short* _B = _A + 4096;                                          \
    bf16x8 af[4], bfr[4];                                                          \
    _Pragma("unroll")                                                              \
    for (int mt = 0; mt < 4; mt++)                                                 \
        af[mt] = *(const bf16x8*)(&_A[(mhalf + mt * 16 + c) * 32 + quad * 8]);     \
    _Pragma("unroll")                                                              \
    for (int nt = 0; nt < 4; nt++)                                                 \
        bfr[nt] = *(const bf16x8*)(&_B[(nhalf + nt * 16 + c) * 32 + quad * 8]);    \
    _Pragma("unroll")                                                              \
    for (int mt = 0; mt < 4; mt++)                                                 \
        _Pragma("unroll")                                                          \
        for (int nt = 0; nt < 4; nt++)                                             \
            acc[mt][nt] = __builtin_amdgcn_mfma_f32_16x16x32_bf16(af[mt], bfr[nt], acc[mt][nt], 0, 0, 0); \
} while (0)

    QKV_STAGE(0, 0);
    QKV_STAGE(1, 1);
    for (int g = 0; g < 10; ++g) {
        const int t = g * 3;
        VMCNT_BAR(4); QKV_STAGE(2, t + 2); QKV_COMPUTE(0);
        VMCNT_BAR(4); QKV_STAGE(0, t + 3); QKV_COMPUTE(1);
        VMCNT_BAR(4); QKV_STAGE(1, t + 4); QKV_COMPUTE(2);
    }
    VMCNT_BAR(4); QKV_COMPUTE(0);
    VMCNT_BAR(0); QKV_COMPUTE(1);

    __syncthreads();

    const int h = (e0 + nhalf) >> 6;
    if (w_idx < 2) {
        unsigned short* Yqk = (w_idx == 0) ? Yq : Yk;
        float* EPf = (float*)pool + wave * 16 * 68;
        const int row = lane >> 2;
        const int cg  = lane & 3;
#pragma unroll
        for (int mt = 0; mt < 4; mt++) {
            LGKM0();
#pragma unroll
            for (int nt = 0; nt < 4; nt++)
#pragma unroll
                for (int r = 0; r < 4; r++)
                    EPf[(quad * 4 + r) * 68 + nt * 16 + c] = acc[mt][nt][r];
            LGKM0();
            float fl[16];
#pragma unroll
            for (int j = 0; j < 4; j++) {
                float4 v = *(const float4*)(&EPf[row * 68 + cg * 16 + j * 4]);
                fl[j * 4 + 0] = v.x; fl[j * 4 + 1] = v.y;
                fl[j * 4 + 2] = v.z; fl[j * 4 + 3] = v.w;
            }
            int m = m0 + mhalf + mt * 16 + row;
            int s = m & (S_LEN - 1);
            int b = m >> 11;
            u16x8 o0, o1;
#pragma unroll
            for (int pi = 0; pi < 8; pi++) {
                int p = cg * 8 + pi;
                float freq  = exp2f(-(float)p * 0.41524101186092034f);
                float angle = (float)s * freq;
                float sn, cs;
                __sincosf(angle, &sn, &cs);
                float ev = fl[2 * pi], ov = fl[2 * pi + 1];
                float re = ev * cs - ov * sn;
                float ro = ev * sn + ov * cs;
                if (pi < 4) { o0[2 * pi] = f2bfu(re); o0[2 * pi + 1] = f2bfu(ro); }
                else        { o1[2 * (pi - 4)] = f2bfu(re); o1[2 * (pi - 4) + 1] = f2bfu(ro); }
            }
            unsigned short* dst = Yqk + (((size_t)(b * NHEADS + h)) * S_LEN + s) * DKH + cg * 16;
            *(u16x8*)(dst)     = o0;
            *(u16x8*)(dst + 8) = o1;
        }
    } else {
        unsigned short* EPb = (unsigned short*)pool + wave * 64 * 72;
        LGKM0();
#pragma unroll
        for (int nt = 0; nt < 4; nt++)
#pragma unroll
            for (int mt = 0; mt < 4; mt++)
#pragma unroll
                for (int r = 0; r < 4; r++)
                    EPb[(nt * 16 + c) * 72 + mt * 16 + quad * 4 + r] = f2bfu(acc[mt][nt][r]);
        LGKM0();
        int mbase = m0 + mhalf;
        int s0 = mbase & (S_LEN - 1);
        int b  = mbase >> 11;
        unsigned short* dst = Yv + (((size_t)(b * NHEADS + h)) * DKH + lane) * S_LEN + s0;
#pragma unroll
        for (int j = 0; j < 8; j++)
            *(u16x8*)(dst + j * 8) = *(const u16x8*)(&EPb[lane * 72 + j * 8]);
    }
#undef QKV_STAGE
#undef QKV_COMPUTE
}

// ---------------------------------------------------------------------------
// Wo MFMA GEMM (R16, kept). Unchanged.
// ---------------------------------------------------------------------------
__global__ __launch_bounds__(256) void gemm_wo(
    const unsigned short* __restrict__ X,
    const unsigned short* __restrict__ Wob,
    float* __restrict__ Yf)
{
    __shared__ __align__(16) unsigned char pool[36864];
    unsigned short* base = (unsigned short*)pool;

    const int tid  = threadIdx.x;
    const int wave = tid >> 6;
    const int lane = tid & 63;
    const int c    = lane & 15;
    const int quad = lane >> 4;

    const int m0 = blockIdx.y * 64;
    const int n0 = blockIdx.x * 128;

    const int mhalf = (wave & 1) * 32;
    const int nhalf = (wave >> 1) * 64;

    f32x4 acc[2][4];
#pragma unroll
    for (int i = 0; i < 2; i++)
#pragma unroll
        for (int j = 0; j < 4; j++) acc[i][j] = (f32x4){0.f, 0.f, 0.f, 0.f};

    const int arow = wave * 16 + (lane >> 2);
    const int brow = wave * 32 + (lane >> 2);
    const int scol = (lane & 3) * 8;
    const unsigned short* Asrc = X   + (size_t)(m0 + arow) * DMODEL + scol;
    const unsigned short* Bsrc = Wob + (size_t)(n0 + brow) * DMODEL + scol;
    const int adoff = arow * 32 + scol;
    const int bdoff = brow * 32 + scol;

#define WO_STAGE(buf, kt) do {                                                     \
    unsigned short* _A = base + (buf) * 6144;                                      \
    unsigned short* _B = _A + 2048;                                                \
    const int _k0 = (kt) * 32;                                                     \
    gload_lds16(Asrc + _k0, _A + adoff);                                           \
    _Pragma("unroll")                                                              \
    for (int _j = 0; _j < 2; _j++)                                                 \
        gload_lds16(Bsrc + (size_t)(_j * 16) * DMODEL + _k0, _B + bdoff + _j * 512);\
} while (0)

#define WO_COMPUTE(buf) do {                                                       \
    const unsigned short* _A = base + (buf) * 6144;                                \
    const unsigned short* _B = _A + 2048;                                          \
    bf16x8 af[2], bfr[4];                                                          \
    _Pragma("unroll")                                                              \
    for (int mt = 0; mt < 2; mt++)                                                 \
        af[mt] = *(const bf16x8*)(&_A[(mhalf + mt * 16 + c) * 32 + quad * 8]);     \
    _Pragma("unroll")                                                              \
    for (int nt = 0; nt < 4; nt++)                                                 \
        bfr[nt] = *(const bf16x8*)(&_B[(nhalf + nt * 16 + c) * 32 + quad * 8]);    \
    _Pragma("unroll")                                                              \
    for (int mt = 0; mt < 2; mt++)                                                 \
        _Pragma("unroll")                                                          \
        for (int nt = 0; nt < 4; nt++)                                             \
            acc[mt][nt] = __builtin_amdgcn_mfma_f32_16x16x32_bf16(af[mt], bfr[nt], acc[mt][nt], 0, 0, 0); \
} while (0)

    WO_STAGE(0, 0);
    WO_STAGE(1, 1);
    for (int g = 0; g < 10; ++g) {
        const int t = g * 3;
        VMCNT_BAR(3); WO_STAGE(2, t + 2); WO_COMPUTE(0);
        VMCNT_BAR(3); WO_STAGE(0, t + 3); WO_COMPUTE(1);
        VMCNT_BAR(3); WO_STAGE(1, t + 4); WO_COMPUTE(2);
    }
    VMCNT_BAR(3); WO_COMPUTE(0);
    VMCNT_BAR(0); WO_COMPUTE(1);

    __syncthreads();

    float* EPf = (float*)pool + wave * 16 * 68;
    const int row = lane >> 2;
    const int cg  = lane & 3;
#pragma unroll
    for (int mt = 0; mt < 2; mt++) {
        LGKM0();
#pragma unroll
        for (int nt = 0; nt < 4; nt++)
#pragma unroll
            for (int r = 0; r < 4; r++)
                EPf[(quad * 4 + r) * 68 + nt * 16 + c] = acc[mt][nt][r];
        LGKM0();
        int m = m0 + mhalf + mt * 16 + row;
        float* dst = Yf + (size_t)m * DMODEL + n0 + nhalf + cg * 16;
#pragma unroll
        for (int j = 0; j < 4; j++)
            *(float4*)(dst + j * 4) = *(const float4*)(&EPf[row * 68 + cg * 16 + j * 4]);
    }
#undef WO_STAGE
#undef WO_COMPUTE
}

// ---------------------------------------------------------------------------
// MFMA flash attention R20 (resubmit): 32-q-row blocks, per-wave independent
// KV halves, barrier-free private loops, LDS epilogue combine. See R20 notes.
// ---------------------------------------------------------------------------
__global__ __launch_bounds__(128, 2) void attn_mfma(
    const unsigned short* __restrict__ Q,
    const unsigned short* __restrict__ K,
    const unsigned short* __restrict__ Vt,
    unsigned short* __restrict__ A,
    float* __restrict__ Scr)
{
    // staging: per (wave,buf): Ks 32x72 u16 (4608B), Vs 64x40 u16 (5120B)
    // layout: Ks wave*9216 + buf*4608 ; Vs 18432 + wave*10240 + buf*5120
    // epilogue overlay: comb [2][32*64] f32 (16KB) + l [2][32] f32 (256B)
    __shared__ __align__(16) unsigned char pool[38912];

    const int tid  = threadIdx.x;
    const int wave = tid >> 6;    // 0..1
    const int lane = tid & 63;
    const int c32  = lane & 31;
    const int hi   = lane >> 5;

    const int bh = blockIdx.x;
    const int b  = bh >> 4;
    const int h  = bh & 15;

    // Piece mapping: R<60 -> split halves (qt 63..34), R>=60 -> singles 33..0
    const int R = (int)blockIdx.y;
    int qt, c_lo, c_hi, spl = 0;
    bool is_split;
    if (R < 60) {
        qt  = 63 - (R >> 1);
        spl = R & 1;
        int n = qt + 1;
        c_lo = spl ? QT_SPLIT : 0;
        c_hi = spl ? n : QT_SPLIT;
        is_split = true;
    } else {
        qt = 93 - R;              // 33..0
        c_lo = 0; c_hi = qt + 1;
        is_split = false;
    }
    const int q0t  = qt * 32;
    const int mlen = c_hi - c_lo;
    const int hf   = (mlen + 1) >> 1;
    const int w_lo = c_lo + (wave ? hf : 0);
    const int w_hi = wave ? c_hi : (c_lo + hf);

    const unsigned short* Qb = Q  + (size_t)bh * S_LEN * DKH;
    const unsigned short* Kb = K  + (size_t)bh * S_LEN * DKH;
    const unsigned short* Vb = Vt + (size_t)bh * DKH * S_LEN;

    // Q B-frags: lane holds Q[q = q0t+c32][dk = t*16 + hi*8 + 0..7]
    bf16x8 qf0 = *(const bf16x8*)(Qb + (size_t)(q0t + c32) * DKH +  0 + hi * 8);
    bf16x8 qf1 = *(const bf16x8*)(Qb + (size_t)(q0t + c32) * DKH + 16 + hi * 8);
    bf16x8 qf2 = *(const bf16x8*)(Qb + (size_t)(q0t + c32) * DKH + 32 + hi * 8);
    bf16x8 qf3 = *(const bf16x8*)(Qb + (size_t)(q0t + c32) * DKH + 48 + hi * 8);

    f32x16 oA, oB;
#pragma unroll
    for (int r = 0; r < 16; r++) { oA[r] = 0.f; oB[r] = 0.f; }
    float lacc = 0.f;

    unsigned short* Ksw = (unsigned short*)(pool + wave * 9216);
    unsigned short* Vsw = (unsigned short*)(pool + 18432 + wave * 10240);

    // per-wave staging: K 32x64 halves (lane -> row lane>>1, 32-half stripe),
    // V 64x32 halves (lane -> dv row, 4x8-half chunks)
    const int krow = lane >> 1;
    const int kcol = (lane & 1) * 32;

    uint4 gK0, gK1, gK2, gK3, gV0, gV1, gV2, gV3;

#define ATT_LOAD(t) do {                                                           \
    const unsigned short* _kp = Kb + (size_t)((t) * 32 + krow) * DKH + kcol;       \
    gK0 = *(const uint4*)(_kp);      gK1 = *(const uint4*)(_kp + 8);               \
    gK2 = *(const uint4*)(_kp + 16); gK3 = *(const uint4*)(_kp + 24);              \
    const unsigned short* _vp = Vb + (size_t)lane * S_LEN + (t) * 32;              \
    gV0 = *(const uint4*)(_vp);      gV1 = *(const uint4*)(_vp + 8);               \
    gV2 = *(const uint4*)(_vp + 16); gV3 = *(const uint4*)(_vp + 24);              \
} while (0)

#define ATT_WRITE(buf) do {                                                        \
    unsigned short* _kd = Ksw + (buf) * 2304 + krow * 72 + kcol;                   \
    *(uint4*)(_kd) = gK0;      *(uint4*)(_kd + 8) = gK1;                           \
    *(uint4*)(_kd + 16) = gK2; *(uint4*)(_kd + 24) = gK3;                          \
    unsigned short* _vd = Vsw + (buf) * 2560 + lane * 40;                          \
    *(uint4*)(_vd) = gV0;      *(uint4*)(_vd + 8) = gV1;                           \
    *(uint4*)(_vd + 16) = gV2; *(uint4*)(_vd + 24) = gV3;                          \
} while (0)

    if (w_lo < w_hi) {
        ATT_LOAD(w_lo);
        ATT_WRITE(0);
        for (int kb = w_lo; kb < w_hi; kb++) {
            const int cur = (kb - w_lo) & 1;
            const int k0  = kb * 32;
            const bool pre = (kb + 1) < w_hi;
            if (pre) ATT_LOAD(kb + 1);      // T14: issue early
            LGKM0();                         // buf[cur] ds_writes complete
            __builtin_amdgcn_sched_barrier(0);

            const unsigned short* Kc = Ksw + cur * 2304;
            const unsigned short* Vc = Vsw + cur * 2560;
            bf16x8 kf0 = *(const bf16x8*)(&Kc[c32 * 72 +  0 + hi * 8]);
            bf16x8 kf1 = *(const bf16x8*)(&Kc[c32 * 72 + 16 + hi * 8]);
            bf16x8 kf2 = *(const bf16x8*)(&Kc[c32 * 72 + 32 + hi * 8]);
            bf16x8 kf3 = *(const bf16x8*)(&Kc[c32 * 72 + 48 + hi * 8]);
            f32x16 s;
#pragma unroll
            for (int r = 0; r < 16; r++) s[r] = 0.f;
            __builtin_amdgcn_s_setprio(1);
            s = __builtin_amdgcn_mfma_f32_32x32x16_bf16(kf0, qf0, s, 0, 0, 0);
            s = __builtin_amdgcn_mfma_f32_32x32x16_bf16(kf1, qf1, s, 0, 0, 0);
            s = __builtin_amdgcn_mfma_f32_32x32x16_bf16(kf2, qf2, s, 0, 0, 0);
            s = __builtin_amdgcn_mfma_f32_32x32x16_bf16(kf3, qf3, s, 0, 0, 0);
            __builtin_amdgcn_s_setprio(0);
            // s[r] = S[key = k0 + (r&3)+8*(r>>2)+4*hi][q = q0t + c32]
            float p[16];
            if (kb < qt) {
#pragma unroll
                for (int r = 0; r < 16; r++) p[r] = __expf(s[r] * 0.125f);
            } else {
                const int qg = q0t + c32;
#pragma unroll
                for (int r = 0; r < 16; r++) {
                    int kg = k0 + (r & 3) + 8 * (r >> 2) + 4 * hi;
                    p[r] = (kg <= qg) ? __expf(s[r] * 0.125f) : 0.0f;
                }
            }
            unsigned pk[8];
#pragma unroll
            for (int i = 0; i < 8; i++) {
                asm("v_cvt_pk_bf16_f32 %0, %1, %2"
                    : "=v"(pk[i]) : "v"(p[2 * i]), "v"(p[2 * i + 1]));
                union { unsigned u; float f; } lo, hx;
                lo.u = pk[i] << 16;
                hx.u = pk[i] & 0xffff0000u;
                lacc += lo.f + hx.f;
            }
            // key-half exchange (verified R19 pattern)
            unsigned f0[4], f1[4];
            {
                unsigned ta, tb;
                ta = (unsigned)__shfl_xor((int)pk[2], 32, 64);
                tb = (unsigned)__shfl_xor((int)pk[0], 32, 64);
                f0[0] = hi ? ta : pk[0];  f0[2] = hi ? pk[2] : tb;
                ta = (unsigned)__shfl_xor((int)pk[3], 32, 64);
                tb = (unsigned)__shfl_xor((int)pk[1], 32, 64);
                f0[1] = hi ? ta : pk[1];  f0[3] = hi ? pk[3] : tb;
                ta = (unsigned)__shfl_xor((int)pk[6], 32, 64);
                tb = (unsigned)__shfl_xor((int)pk[4], 32, 64);
                f1[0] = hi ? ta : pk[4];  f1[2] = hi ? pk[6] : tb;
                ta = (unsigned)__shfl_xor((int)pk[7], 32, 64);
                tb = (unsigned)__shfl_xor((int)pk[5], 32, 64);
                f1[1] = hi ? ta : pk[5];  f1[3] = hi ? pk[7] : tb;
            }
            union { unsigned u[4]; bf16x8 v; } pa0, pa1;
            pa0.u[0] = f0[0]; pa0.u[1] = f0[1]; pa0.u[2] = f0[2]; pa0.u[3] = f0[3];
            pa1.u[0] = f1[0]; pa1.u[1] = f1[1]; pa1.u[2] = f1[2]; pa1.u[3] = f1[3];
            bf16x8 v00 = *(const bf16x8*)(&Vc[(c32)      * 40 +  0 + hi * 8]);
            bf16x8 v10 = *(const bf16x8*)(&Vc[(c32)      * 40 + 16 + hi * 8]);
            bf16x8 v01 = *(const bf16x8*)(&Vc[(32 + c32) * 40 +  0 + hi * 8]);
            bf16x8 v11 = *(const bf16x8*)(&Vc[(32 + c32) * 40 + 16 + hi * 8]);
            __builtin_amdgcn_s_setprio(1);
            oA = __builtin_amdgcn_mfma_f32_32x32x16_bf16(pa0.v, v00, oA, 0, 0, 0);
            oA = __builtin_amdgcn_mfma_f32_32x32x16_bf16(pa1.v, v10, oA, 0, 0, 0);
            oB = __builtin_amdgcn_mfma_f32_32x32x16_bf16(pa0.v, v01, oB, 0, 0, 0);
            oB = __builtin_amdgcn_mfma_f32_32x32x16_bf16(pa1.v, v11, oB, 0, 0, 0);
            __builtin_amdgcn_s_setprio(0);

            if (pre) ATT_WRITE(cur ^ 1);     // T14: write late (vmcnt paid here)
        }
    }
#undef ATT_LOAD
#undef ATT_WRITE

    // full l for q = q0t+c32 over THIS wave's chunk
    lacc += __shfl_xor(lacc, 32, 64);

    // epilogue: combine the two wave-halves in LDS
    __syncthreads();                 // both waves done with staging LDS
    float* comb = (float*)pool;      // [2][32*64]
    float* lc   = (float*)pool + 2 * 2048;   // [2][32]
#pragma unroll
    for (int r = 0; r < 16; r++) {
        int qr = (r & 3) + 8 * (r >> 2) + 4 * hi;
        comb[wave * 2048 + qr * 64 + c32]      = oA[r];
        comb[wave * 2048 + qr * 64 + 32 + c32] = oB[r];
    }
    if (hi == 0) lc[wave * 32 + c32] = lacc;
    __syncthreads();

    const int row = wave * 16 + (lane >> 2);   // 0..31
    const int cg  = (lane & 3) * 16;
    float lsum = lc[row] + lc[32 + row];
    float vals[16];
#pragma unroll
    for (int j = 0; j < 4; j++) {
        float4 a0 = *(const float4*)(&comb[row * 64 + cg + j * 4]);
        float4 a1 = *(const float4*)(&comb[2048 + row * 64 + cg + j * 4]);
        vals[j * 4 + 0] = a0.x + a1.x; vals[j * 4 + 1] = a0.y + a1.y;
        vals[j * 4 + 2] = a0.z + a1.z; vals[j * 4 + 3] = a0.w + a1.w;
    }
    if (!is_split) {
        float inv = 1.0f / lsum;
        u16x8 o0, o1;
#pragma unroll
        for (int j = 0; j < 8; j++) { o0[j] = f2bfu(vals[j] * inv); o1[j] = f2bfu(vals[8 + j] * inv); }
        int s = q0t + row;
        unsigned short* Ap = A + ((size_t)b * S_LEN + s) * DMODEL + h * DKH + cg;
        *(u16x8*)(Ap)     = o0;
        *(u16x8*)(Ap + 8) = o1;
    } else {
        const int slot = (bh * 30 + (qt - QT_SPLIT)) * 2 + spl;
        float* Po = Scr + (size_t)slot * 2048;
#pragma unroll
        for (int j = 0; j < 4; j++)
            *(float4*)(&Po[row * 64 + cg + j * 4]) =
                (float4){vals[j * 4 + 0], vals[j * 4 + 1], vals[j * 4 + 2], vals[j * 4 + 3]};
        if ((lane & 3) == 0) Scr[PO2_FLOATS + (size_t)slot * 32 + row] = lsum;
    }
}

// ---------------------------------------------------------------------------
// Combine split partials: A = (o0+o1)/(l0+l1) for qt >= 34. 960 x 128 thr.
// ---------------------------------------------------------------------------
__global__ __launch_bounds__(128) void attn_combine(
    const float* __restrict__ Scr, unsigned short* __restrict__ A)
{
    const int bx  = blockIdx.x;       // 0 .. 32*30-1
    const int bh  = bx / 30;
    const int qtm = bx % 30;
    const int qt  = QT_SPLIT + qtm;
    const int b   = bh >> 4;
    const int h   = bh & 15;

    const int slot0 = (bh * 30 + qtm) * 2;
    const float* O0 = Scr + (size_t)slot0 * 2048;
    const float* O1 = O0 + 2048;
    const float* L0 = Scr + PO2_FLOATS + (size_t)slot0 * 32;
    const float* L1 = L0 + 32;

    const int r  = threadIdx.x >> 2;          // 0..31
    const int cg = (threadIdx.x & 3) * 16;

    float inv = 1.0f / (L0[r] + L1[r]);

    u16x8 outv[2];
#pragma unroll
    for (int half = 0; half < 2; half++) {
        float4 a0 = *(const float4*)(O0 + r * 64 + cg + half * 8);
        float4 b0 = *(const float4*)(O0 + r * 64 + cg + half * 8 + 4);
        float4 a1 = *(const float4*)(O1 + r * 64 + cg + half * 8);
        float4 b1 = *(const float4*)(O1 + r * 64 + cg + half * 8 + 4);
        outv[half][0] = f2bfu((a0.x + a1.x) * inv);
        outv[half][1] = f2bfu((a0.y + a1.y) * inv);
        outv[half][2] = f2bfu((a0.z + a1.z) * inv);
        outv[half][3] = f2bfu((a0.w + a1.w) * inv);
        outv[half][4] = f2bfu((b0.x + b1.x) * inv);
        outv[half][5] = f2bfu((b0.y + b1.y) * inv);
        outv[half][6] = f2bfu((b0.z + b1.z) * inv);
        outv[half][7] = f2bfu((b0.w + b1.w) * inv);
    }
    const int s = qt * 32 + r;
    unsigned short* Ap = A + ((size_t)b * S_LEN + s) * DMODEL + h * DKH + cg;
    *(u16x8*)(Ap)     = outv[0];
    *(u16x8*)(Ap + 8) = outv[1];
}

extern "C" void kernel_launch(void* const* d_in, const int* in_sizes, int n_in,
                              void* d_out, int out_size, void* d_ws, size_t ws_size,
                              hipStream_t stream) {
    const float* x  = (const float*)d_in[0];
    const float* Wq = (const float*)d_in[1];
    const float* Wk = (const float*)d_in[2];
    const float* Wv = (const float*)d_in[3];
    const float* Wo = (const float*)d_in[4];
    float* out = (float*)d_out;

    unsigned short* Qw = (unsigned short*)d_ws;
    unsigned short* Kw = Qw + (size_t)MROWS * DMODEL;
    unsigned short* Vw = Kw + (size_t)MROWS * DMODEL;
    unsigned short* Wb = Vw + (size_t)MROWS * DMODEL;
    unsigned short* Aw = Wb;    // aliased; QKV completes before attn writes A
    unsigned short* Wob = Qw;   // aliased; Q dead after attn_mfma
    unsigned short* Xb = (unsigned short*)d_out;
    float* Scr = (float*)d_out;

    cvt_all<<<dim3(DMODEL * DMODEL / (256 * 8), 7), 256, 0, stream>>>(Wq, Wk, Wv, x, Wb, Xb);

    gemm_qkv<<<dim3(3 * DMODEL / 128, MROWS / 128), 256, 0, stream>>>(
        Xb, Wb, Qw, Kw, Vw);

    attn_mfma<<<dim3(NHEADS * BATCH, NPIECE_Y), 128, 0, stream>>>(Qw, Kw, Vw, Aw, Scr);

    attn_combine<<<dim3(NHEADS * BATCH * 30), 128, 0, stream>>>(Scr, Aw);

    cvt_wo<<<dim3(DMODEL * DMODEL / (256 * 8)), 256, 0, stream>>>(Wo, Wob);

    gemm_wo<<<dim3(DMODEL / 128, MROWS / 64), 256, 0, stream>>>(Aw, Wob, out);
}

// Round 9
// 177.708 us; speedup vs baseline: 1.1338x; 1.1338x over previous
//
#include <hip/hip_runtime.h>
#include <hip/hip_bf16.h>
#include <math.h>

// Problem constants
#define S_LEN   2048
#define BATCH   2
#define DMODEL  1024
#define NHEADS  16
#define DKH     64
#define MROWS   (BATCH * S_LEN)   // 4096

// attn split-KV geometry (R19, measured-best): QBLK=64, KVBLK=32.
// qb 0..16 single block; qb 17..31 two halves. Pieces/bh = 47; partial
// slots/bh = 30 -> 960 slots x (64x64 o + 64 l) fp32 in d_out.
#define SPLIT_Q0   17
#define NPIECE     47
#define SLOTS_BH   30
#define PO_FLOATS  (960 * 4096)

typedef __attribute__((ext_vector_type(8)))  __bf16 bf16x8;
typedef __attribute__((ext_vector_type(4)))  float  f32x4;
typedef __attribute__((ext_vector_type(16))) float  f32x16;
typedef __attribute__((ext_vector_type(8)))  unsigned short u16x8;
typedef __attribute__((ext_vector_type(2)))  unsigned int   u32x2;

__device__ __forceinline__ float bfu2f(unsigned short u) {
    union { unsigned int i; float f; } v;
    v.i = ((unsigned int)u) << 16;
    return v.f;
}

__device__ __forceinline__ unsigned short f2bfu(float f) {
    union { __bf16 h; unsigned short u; } v;
    v.h = (__bf16)f;    // native RNE cvt
    return v.u;
}

#define LGKM0() __builtin_amdgcn_s_waitcnt(0xc07f)   // lgkmcnt(0), vmcnt free

// counted-vmcnt + raw barrier (T4)
#define VMCNT_BAR(n) do {                                        \
    asm volatile("s_waitcnt vmcnt(" #n ")" ::: "memory");        \
    __builtin_amdgcn_s_barrier();                                \
    __builtin_amdgcn_sched_barrier(0);                           \
} while (0)

// global -> LDS direct DMA, 16B per lane
__device__ __forceinline__ void gload_lds16(const void* g, void* l) {
    __builtin_amdgcn_global_load_lds(
        (const __attribute__((address_space(1))) void*)g,
        (__attribute__((address_space(3))) void*)l, 16, 0, 0);
}

// ---------------------------------------------------------------------------
// Pre-convert: Wq/Wk/Wv -> bf16 (ws) and x -> bf16 (d_out scratch).
// ---------------------------------------------------------------------------
__global__ __launch_bounds__(256) void cvt_all(
    const float* __restrict__ W0, const float* __restrict__ W1, const float* __restrict__ W2,
    const float* __restrict__ X,
    unsigned short* __restrict__ Wb, unsigned short* __restrict__ Xb)
{
    const int y = blockIdx.y;
    const float* src;
    unsigned short* dst;
    if (y < 3) {
        src = (y == 0) ? W0 : (y == 1) ? W1 : W2;
        dst = Wb + (size_t)y * (DMODEL * DMODEL);
    } else {
        src = X + (size_t)(y - 3) * (DMODEL * DMODEL);
        dst = Xb + (size_t)(y - 3) * (DMODEL * DMODEL);
    }
    size_t idx = ((size_t)blockIdx.x * 256 + threadIdx.x) * 8;
    float4 a = *(const float4*)(src + idx);
    float4 b = *(const float4*)(src + idx + 4);
    u16x8 h;
    h[0] = f2bfu(a.x); h[1] = f2bfu(a.y); h[2] = f2bfu(a.z); h[3] = f2bfu(a.w);
    h[4] = f2bfu(b.x); h[5] = f2bfu(b.y); h[6] = f2bfu(b.z); h[7] = f2bfu(b.w);
    *(u16x8*)(dst + idx) = h;
}

// ---------------------------------------------------------------------------
// QKV MFMA GEMM (R16, measured-best): 3-buffer counted-vmcnt. Unchanged.
// ---------------------------------------------------------------------------
__global__ __launch_bounds__(256) void gemm_qkv(
    const unsigned short* __restrict__ Xb,
    const unsigned short* __restrict__ Wb,
    unsigned short* __restrict__ Yq, unsigned short* __restrict__ Yk, unsigned short* __restrict__ Yv)
{
    __shared__ __align__(16) unsigned char pool[49152];
    unsigned short* base = (unsigned short*)pool;

    const int tid  = threadIdx.x;
    const int wave = tid >> 6;
    const int lane = tid & 63;
    const int c    = lane & 15;
    const int quad = lane >> 4;

    const int m0 = blockIdx.y * 128;
    const int n0 = blockIdx.x * 128;
    const int w_idx = n0 >> 10;
    const int e0    = n0 & 1023;
    const unsigned short* Wsrc = Wb + (size_t)w_idx * (DMODEL * DMODEL);

    const int mhalf = (wave & 1) * 64;
    const int nhalf = (wave >> 1) * 64;

    f32x4 acc[4][4];
#pragma unroll
    for (int i = 0; i < 4; i++)
#pragma unroll
        for (int j = 0; j < 4; j++) acc[i][j] = (f32x4){0.f, 0.f, 0.f, 0.f};

    const int srow = wave * 32 + (lane >> 2);
    const int scol = (lane & 3) * 8;
    const unsigned short* Asrc = Xb   + (size_t)(m0 + srow) * DMODEL + scol;
    const unsigned short* Bsrc = Wsrc + (size_t)(e0 + srow) * DMODEL + scol;
    const int doff = srow * 32 + scol;

#define QKV_STAGE(buf, kt) do {                                                    \
    unsigned short* _A = base + (buf) * 8192;                                      \
    unsigned short* _B = _A + 4096;                                                \
    const int _k0 = (kt) * 32;                                                     \
    _Pragma("unroll")                                                              \
    for (int _j = 0; _j < 2; _j++) {                                               \
        gload_lds16(Asrc + (size_t)(_j * 16) * DMODEL + _k0, _A + doff + _j * 512);\
        gload_lds16(Bsrc + (size_t)(_j * 16) * DMODEL + _k0, _B + doff + _j * 512);\
    }                                                                              \
} while (0)

#define QKV_COMPUTE(buf) do {                                                      \
    const unsigned short* _A = base + (buf) * 8192;                                \
    const unsigned short* _B = _A + 4096;                                          \
    bf16x8 af[4], bfr[4];                                                          \
    _Pragma("unroll")                                                              \
    for (int mt = 0; mt < 4; mt++)                                                 \
        af[mt] = *(const bf16x8*)(&_A[(mhalf + mt * 16 + c) * 32 + quad * 8]);     \
    _Pragma("unroll")                                                              \
    for (int nt = 0; nt < 4; nt++)                                                 \
        bfr[nt] = *(const bf16x8*)(&_B[(nhalf + nt * 16 + c) * 32 + quad * 8]);    \
    _Pragma("unroll")                                                              \
    for (int mt = 0; mt < 4; mt++)                                                 \
        _Pragma("unroll")                                                          \
        for (int nt = 0; nt < 4; nt++)                                             \
            acc[mt][nt] = __builtin_amdgcn_mfma_f32_16x16x32_bf16(af[mt], bfr[nt], acc[mt][nt], 0, 0, 0); \
} while (0)

    QKV_STAGE(0, 0);
    QKV_STAGE(1, 1);
    for (int g = 0; g < 10; ++g) {
        const int t = g * 3;
        VMCNT_BAR(4); QKV_STAGE(2, t + 2); QKV_COMPUTE(0);
        VMCNT_BAR(4); QKV_STAGE(0, t + 3); QKV_COMPUTE(1);
        VMCNT_BAR(4); QKV_STAGE(1, t + 4); QKV_COMPUTE(2);
    }
    VMCNT_BAR(4); QKV_COMPUTE(0);
    VMCNT_BAR(0); QKV_COMPUTE(1);

    __syncthreads();

    const int h = (e0 + nhalf) >> 6;
    if (w_idx < 2) {
        unsigned short* Yqk = (w_idx == 0) ? Yq : Yk;
        float* EPf = (float*)pool + wave * 16 * 68;
        const int row = lane >> 2;
        const int cg  = lane & 3;
#pragma unroll
        for (int mt = 0; mt < 4; mt++) {
            LGKM0();
#pragma unroll
            for (int nt = 0; nt < 4; nt++)
#pragma unroll
                for (int r = 0; r < 4; r++)
                    EPf[(quad * 4 + r) * 68 + nt * 16 + c] = acc[mt][nt][r];
            LGKM0();
            float fl[16];
#pragma unroll
            for (int j = 0; j < 4; j++) {
                float4 v = *(const float4*)(&EPf[row * 68 + cg * 16 + j * 4]);
                fl[j * 4 + 0] = v.x; fl[j * 4 + 1] = v.y;
                fl[j * 4 + 2] = v.z; fl[j * 4 + 3] = v.w;
            }
            int m = m0 + mhalf + mt * 16 + row;
            int s = m & (S_LEN - 1);
            int b = m >> 11;
            u16x8 o0, o1;
#pragma unroll
            for (int pi = 0; pi < 8; pi++) {
                int p = cg * 8 + pi;
                float freq  = exp2f(-(float)p * 0.41524101186092034f);
                float angle = (float)s * freq;
                float sn, cs;
                __sincosf(angle, &sn, &cs);
                float ev = fl[2 * pi], ov = fl[2 * pi + 1];
                float re = ev * cs - ov * sn;
                float ro = ev * sn + ov * cs;
                if (pi < 4) { o0[2 * pi] = f2bfu(re); o0[2 * pi + 1] = f2bfu(ro); }
                else        { o1[2 * (pi - 4)] = f2bfu(re); o1[2 * (pi - 4) + 1] = f2bfu(ro); }
            }
            unsigned short* dst = Yqk + (((size_t)(b * NHEADS + h)) * S_LEN + s) * DKH + cg * 16;
            *(u16x8*)(dst)     = o0;
            *(u16x8*)(dst + 8) = o1;
        }
    } else {
        unsigned short* EPb = (unsigned short*)pool + wave * 64 * 72;
        LGKM0();
#pragma unroll
        for (int nt = 0; nt < 4; nt++)
#pragma unroll
            for (int mt = 0; mt < 4; mt++)
#pragma unroll
                for (int r = 0; r < 4; r++)
                    EPb[(nt * 16 + c) * 72 + mt * 16 + quad * 4 + r] = f2bfu(acc[mt][nt][r]);
        LGKM0();
        int mbase = m0 + mhalf;
        int s0 = mbase & (S_LEN - 1);
        int b  = mbase >> 11;
        unsigned short* dst = Yv + (((size_t)(b * NHEADS + h)) * DKH + lane) * S_LEN + s0;
#pragma unroll
        for (int j = 0; j < 8; j++)
            *(u16x8*)(dst + j * 8) = *(const u16x8*)(&EPb[lane * 72 + j * 8]);
    }
#undef QKV_STAGE
#undef QKV_COMPUTE
}

// ---------------------------------------------------------------------------
// Wo MFMA GEMM (R16, kept). Unchanged.
// ---------------------------------------------------------------------------
__global__ __launch_bounds__(256) void gemm_wo(
    const unsigned short* __restrict__ X,
    const unsigned short* __restrict__ Wob,
    float* __restrict__ Yf)
{
    __shared__ __align__(16) unsigned char pool[36864];
    unsigned short* base = (unsigned short*)pool;

    const int tid  = threadIdx.x;
    const int wave = tid >> 6;
    const int lane = tid & 63;
    const int c    = lane & 15;
    const int quad = lane >> 4;

    const int m0 = blockIdx.y * 64;
    const int n0 = blockIdx.x * 128;

    const int mhalf = (wave & 1) * 32;
    const int nhalf = (wave >> 1) * 64;

    f32x4 acc[2][4];
#pragma unroll
    for (int i = 0; i < 2; i++)
#pragma unroll
        for (int j = 0; j < 4; j++) acc[i][j] = (f32x4){0.f, 0.f, 0.f, 0.f};

    const int arow = wave * 16 + (lane >> 2);
    const int brow = wave * 32 + (lane >> 2);
    const int scol = (lane & 3) * 8;
    const unsigned short* Asrc = X   + (size_t)(m0 + arow) * DMODEL + scol;
    const unsigned short* Bsrc = Wob + (size_t)(n0 + brow) * DMODEL + scol;
    const int adoff = arow * 32 + scol;
    const int bdoff = brow * 32 + scol;

#define WO_STAGE(buf, kt) do {                                                     \
    unsigned short* _A = base + (buf) * 6144;                                      \
    unsigned short* _B = _A + 2048;                                                \
    const int _k0 = (kt) * 32;                                                     \
    gload_lds16(Asrc + _k0, _A + adoff);                                           \
    _Pragma("unroll")                                                              \
    for (int _j = 0; _j < 2; _j++)                                                 \
        gload_lds16(Bsrc + (size_t)(_j * 16) * DMODEL + _k0, _B + bdoff + _j * 512);\
} while (0)

#define WO_COMPUTE(buf) do {                                                       \
    const unsigned short* _A = base + (buf) * 6144;                                \
    const unsigned short* _B = _A + 2048;                                          \
    bf16x8 af[2], bfr[4];                                                          \
    _Pragma("unroll")                                                              \
    for (int mt = 0; mt < 2; mt++)                                                 \
        af[mt] = *(const bf16x8*)(&_A[(mhalf + mt * 16 + c) * 32 + quad * 8]);     \
    _Pragma("unroll")                                                              \
    for (int nt = 0; nt < 4; nt++)                                                 \
        bfr[nt] = *(const bf16x8*)(&_B[(nhalf + nt * 16 + c) * 32 + quad * 8]);    \
    _Pragma("unroll")                                                              \
    for (int mt = 0; mt < 2; mt++)                                                 \
        _Pragma("unroll")                                                          \
        for (int nt = 0; nt < 4; nt++)                                             \
            acc[mt][nt] = __builtin_amdgcn_mfma_f32_16x16x32_bf16(af[mt], bfr[nt], acc[mt][nt], 0, 0, 0); \
} while (0)

    WO_STAGE(0, 0);
    WO_STAGE(1, 1);
    for (int g = 0; g < 10; ++g) {
        const int t = g * 3;
        VMCNT_BAR(3); WO_STAGE(2, t + 2); WO_COMPUTE(0);
        VMCNT_BAR(3); WO_STAGE(0, t + 3); WO_COMPUTE(1);
        VMCNT_BAR(3); WO_STAGE(1, t + 4); WO_COMPUTE(2);
    }
    VMCNT_BAR(3); WO_COMPUTE(0);
    VMCNT_BAR(0); WO_COMPUTE(1);

    __syncthreads();

    float* EPf = (float*)pool + wave * 16 * 68;
    const int row = lane >> 2;
    const int cg  = lane & 3;
#pragma unroll
    for (int mt = 0; mt < 2; mt++) {
        LGKM0();
#pragma unroll
        for (int nt = 0; nt < 4; nt++)
#pragma unroll
            for (int r = 0; r < 4; r++)
                EPf[(quad * 4 + r) * 68 + nt * 16 + c] = acc[mt][nt][r];
        LGKM0();
        int m = m0 + mhalf + mt * 16 + row;
        float* dst = Yf + (size_t)m * DMODEL + n0 + nhalf + cg * 16;
#pragma unroll
        for (int j = 0; j < 4; j++)
            *(float4*)(dst + j * 4) = *(const float4*)(&EPf[row * 68 + cg * 16 + j * 4]);
    }
#undef WO_STAGE
#undef WO_COMPUTE
}

// ---------------------------------------------------------------------------
// MFMA flash attention R21 = verified R19 (32x32x16 swapped-QK, split-KV,
// 44.4us measured) with ONE change: the key-half exchange uses 4x
// v_permlane32_swap_b32 instead of 8x shfl_xor + selects.
//   new_a = [a.lo, b.lo], new_b = [a.hi, b.hi]  (dst.hi <-> src.lo swap)
//   => {f0[0], f0[2]} = swap(pk0, pk2), etc.  (T12 primitive, m255)
// R20 lesson logged: occupancy-halving restructures lose; R19 revert.
// ---------------------------------------------------------------------------
__global__ __launch_bounds__(128, 4) void attn_mfma(
    const unsigned short* __restrict__ Q,
    const unsigned short* __restrict__ K,
    const unsigned short* __restrict__ Vt,
    unsigned short* __restrict__ A,
    float* __restrict__ Scr)
{
    __shared__ unsigned short Ks[2][32 * 72];   // [key][dk], stride 72
    __shared__ unsigned short Vs[2][64 * 40];   // [dv][key], stride 40

    const int tid  = threadIdx.x;
    const int wave = tid >> 6;    // 0..1
    const int lane = tid & 63;
    const int c32  = lane & 31;
    const int hi   = lane >> 5;

    const int bh = blockIdx.x;
    const int b  = bh >> 4;
    const int h  = bh & 15;

    // Piece mapping (identical to R18/R19)
    const int R = (int)blockIdx.y;
    int qb, t_lo, t_hi, spl = 0;
    bool is_split;
    if (R <= 16) {
        qb = 16 - R; t_lo = 0; t_hi = 2 * qb + 2; is_split = false;
    } else {
        int i = R - 17;
        qb  = 31 - (i >> 1);
        spl = i & 1;
        int nk = 2 * qb + 2, half = nk >> 1;
        t_lo = spl ? half : 0;
        t_hi = spl ? nk   : half;
        is_split = true;
    }
    const int q0b = qb * 64;
    const int q0w = q0b + wave * 32;

    const unsigned short* Qb = Q  + (size_t)bh * S_LEN * DKH;
    const unsigned short* Kb = K  + (size_t)bh * S_LEN * DKH;
    const unsigned short* Vb = Vt + (size_t)bh * DKH * S_LEN;

    // Q B-frags: lane holds Q[q = q0w+c32][dk = t*16 + hi*8 + 0..7]
    bf16x8 qf0 = *(const bf16x8*)(Qb + (size_t)(q0w + c32) * DKH +  0 + hi * 8);
    bf16x8 qf1 = *(const bf16x8*)(Qb + (size_t)(q0w + c32) * DKH + 16 + hi * 8);
    bf16x8 qf2 = *(const bf16x8*)(Qb + (size_t)(q0w + c32) * DKH + 32 + hi * 8);
    bf16x8 qf3 = *(const bf16x8*)(Qb + (size_t)(q0w + c32) * DKH + 48 + hi * 8);

    f32x16 oA, oB;
#pragma unroll
    for (int r = 0; r < 16; r++) { oA[r] = 0.f; oB[r] = 0.f; }
    float lacc = 0.f;

    const int my_nkb = (q0w >> 5) + 1;   // tiles this wave computes
    const int kbf    = q0w >> 5;         // tiles < kbf are mask-free

    // staging (128 threads): K 32x64 halves, V 64x32 halves; 2 uint4 each
    const int krow = tid >> 2;           // 0..31
    const int kcol = (tid & 3) * 16;     // 0,16,32,48
    const int vrow = tid >> 1;           // 0..63
    const int vcol = (tid & 1) * 16;     // 0,16

    uint4 gK0 = *(const uint4*)(Kb + (size_t)(t_lo * 32 + krow) * DKH + kcol);
    uint4 gK1 = *(const uint4*)(Kb + (size_t)(t_lo * 32 + krow) * DKH + kcol + 8);
    uint4 gV0 = *(const uint4*)(Vb + (size_t)vrow * S_LEN + t_lo * 32 + vcol);
    uint4 gV1 = *(const uint4*)(Vb + (size_t)vrow * S_LEN + t_lo * 32 + vcol + 8);
    *(uint4*)(&Ks[t_lo & 1][krow * 72 + kcol])     = gK0;
    *(uint4*)(&Ks[t_lo & 1][krow * 72 + kcol + 8]) = gK1;
    *(uint4*)(&Vs[t_lo & 1][vrow * 40 + vcol])     = gV0;
    *(uint4*)(&Vs[t_lo & 1][vrow * 40 + vcol + 8]) = gV1;

    for (int kb = t_lo; kb < t_hi; kb++) {
        const int k0 = kb * 32;
        const int nb = kb + 1;
        const bool pre = nb < t_hi;
        __syncthreads();
        if (pre) {   // T14: issue loads now, LDS-write at end of iter
            gK0 = *(const uint4*)(Kb + (size_t)(nb * 32 + krow) * DKH + kcol);
            gK1 = *(const uint4*)(Kb + (size_t)(nb * 32 + krow) * DKH + kcol + 8);
            gV0 = *(const uint4*)(Vb + (size_t)vrow * S_LEN + nb * 32 + vcol);
            gV1 = *(const uint4*)(Vb + (size_t)vrow * S_LEN + nb * 32 + vcol + 8);
        }
        if (kb < my_nkb) {
            const unsigned short* Kc = &Ks[kb & 1][0];
            const unsigned short* Vc = &Vs[kb & 1][0];
            bf16x8 kf0 = *(const bf16x8*)(&Kc[c32 * 72 +  0 + hi * 8]);
            bf16x8 kf1 = *(const bf16x8*)(&Kc[c32 * 72 + 16 + hi * 8]);
            bf16x8 kf2 = *(const bf16x8*)(&Kc[c32 * 72 + 32 + hi * 8]);
            bf16x8 kf3 = *(const bf16x8*)(&Kc[c32 * 72 + 48 + hi * 8]);
            f32x16 s;
#pragma unroll
            for (int r = 0; r < 16; r++) s[r] = 0.f;
            __builtin_amdgcn_s_setprio(1);
            s = __builtin_amdgcn_mfma_f32_32x32x16_bf16(kf0, qf0, s, 0, 0, 0);
            s = __builtin_amdgcn_mfma_f32_32x32x16_bf16(kf1, qf1, s, 0, 0, 0);
            s = __builtin_amdgcn_mfma_f32_32x32x16_bf16(kf2, qf2, s, 0, 0, 0);
            s = __builtin_amdgcn_mfma_f32_32x32x16_bf16(kf3, qf3, s, 0, 0, 0);
            __builtin_amdgcn_s_setprio(0);
            // s[r] = S[key = k0 + (r&3)+8*(r>>2)+4*hi][q = q0w + c32]
            float p[16];
            if (kb < kbf) {
#pragma unroll
                for (int r = 0; r < 16; r++) p[r] = __expf(s[r] * 0.125f);
            } else {
                const int qg = q0w + c32;
#pragma unroll
                for (int r = 0; r < 16; r++) {
                    int kg = k0 + (r & 3) + 8 * (r >> 2) + 4 * hi;
                    p[r] = (kg <= qg) ? __expf(s[r] * 0.125f) : 0.0f;
                }
            }
            // pack to bf16 pairs; accumulate l from ROUNDED values
            unsigned pk[8];
#pragma unroll
            for (int i = 0; i < 8; i++) {
                asm("v_cvt_pk_bf16_f32 %0, %1, %2"
                    : "=v"(pk[i]) : "v"(p[2 * i]), "v"(p[2 * i + 1]));
                union { unsigned u; float f; } lo, hx;
                lo.u = pk[i] << 16;
                hx.u = pk[i] & 0xffff0000u;
                lacc += lo.f + hx.f;
            }
            // key-half exchange via permlane32_swap (replaces 8x shfl_xor):
            // swap(a,b): new_a = [a.lo, b.lo], new_b = [a.hi, b.hi]
            u32x2 s02 = __builtin_amdgcn_permlane32_swap(pk[0], pk[2], false, false);
            u32x2 s13 = __builtin_amdgcn_permlane32_swap(pk[1], pk[3], false, false);
            u32x2 s46 = __builtin_amdgcn_permlane32_swap(pk[4], pk[6], false, false);
            u32x2 s57 = __builtin_amdgcn_permlane32_swap(pk[5], pk[7], false, false);
            union { unsigned u[4]; bf16x8 v; } pa0, pa1;
            pa0.u[0] = s02[0]; pa0.u[1] = s13[0]; pa0.u[2] = s02[1]; pa0.u[3] = s13[1];
            pa1.u[0] = s46[0]; pa1.u[1] = s57[0]; pa1.u[2] = s46[1]; pa1.u[3] = s57[1];
            bf16x8 v00 = *(const bf16x8*)(&Vc[(c32)      * 40 +  0 + hi * 8]);
            bf16x8 v10 = *(const bf16x8*)(&Vc[(c32)      * 40 + 16 + hi * 8]);
            bf16x8 v01 = *(const bf16x8*)(&Vc[(32 + c32) * 40 +  0 + hi * 8]);
            bf16x8 v11 = *(const bf16x8*)(&Vc[(32 + c32) * 40 + 16 + hi * 8]);
            __builtin_amdgcn_s_setprio(1);
            oA = __builtin_amdgcn_mfma_f32_32x32x16_bf16(pa0.v, v00, oA, 0, 0, 0);
            oA = __builtin_amdgcn_mfma_f32_32x32x16_bf16(pa1.v, v10, oA, 0, 0, 0);
            oB = __builtin_amdgcn_mfma_f32_32x32x16_bf16(pa0.v, v01, oB, 0, 0, 0);
            oB = __builtin_amdgcn_mfma_f32_32x32x16_bf16(pa1.v, v11, oB, 0, 0, 0);
            __builtin_amdgcn_s_setprio(0);
        }
        if (pre) {   // LDS write after compute (vmcnt paid post-overlap)
            *(uint4*)(&Ks[nb & 1][krow * 72 + kcol])     = gK0;
            *(uint4*)(&Ks[nb & 1][krow * 72 + kcol + 8]) = gK1;
            *(uint4*)(&Vs[nb & 1][vrow * 40 + vcol])     = gV0;
            *(uint4*)(&Vs[nb & 1][vrow * 40 + vcol + 8]) = gV1;
        }
    }

    // combine halves: full l for q = q0w + c32 at every lane
    lacc += __shfl_xor(lacc, 32, 64);

    if (!is_split) {
        float inv = 1.0f / lacc;
#pragma unroll
        for (int r = 0; r < 16; r++) {
            int qr = (r & 3) + 8 * (r >> 2) + 4 * hi;   // output q-row of reg r
            float invr = __shfl(inv, qr, 64);
            int sg = q0w + qr;
            unsigned short* Ap = A + ((size_t)b * S_LEN + sg) * DMODEL + h * DKH;
            Ap[c32]      = f2bfu(oA[r] * invr);
            Ap[32 + c32] = f2bfu(oB[r] * invr);
        }
    } else {
        const int slot = bh * SLOTS_BH + (qb - SPLIT_Q0) * 2 + spl;
        float* Po = Scr + (size_t)slot * 4096;
        float* Pl = Scr + PO_FLOATS + (size_t)slot * 64;
#pragma unroll
        for (int r = 0; r < 16; r++) {
            int qr  = (r & 3) + 8 * (r >> 2) + 4 * hi;
            int row = wave * 32 + qr;
            Po[row * 64 + c32]      = oA[r];
            Po[row * 64 + 32 + c32] = oB[r];
        }
        if (hi == 0) Pl[wave * 32 + c32] = lacc;
    }
}

// ---------------------------------------------------------------------------
// Merged combine + Wo-convert (saves one launch): blocks [0,480) combine
// split partials A = (o0+o1)/(l0+l1); blocks [480,992) convert Wo -> bf16.
// ---------------------------------------------------------------------------
__global__ __launch_bounds__(256) void combine_cvtwo(
    const float* __restrict__ Scr, unsigned short* __restrict__ A,
    const float* __restrict__ Wo, unsigned short* __restrict__ Wob)
{
    if (blockIdx.x >= 480) {
        size_t idx = ((size_t)(blockIdx.x - 480) * 256 + threadIdx.x) * 8;
        float4 a = *(const float4*)(Wo + idx);
        float4 b = *(const float4*)(Wo + idx + 4);
        u16x8 hh;
        hh[0] = f2bfu(a.x); hh[1] = f2bfu(a.y); hh[2] = f2bfu(a.z); hh[3] = f2bfu(a.w);
        hh[4] = f2bfu(b.x); hh[5] = f2bfu(b.y); hh[6] = f2bfu(b.z); hh[7] = f2bfu(b.w);
        *(u16x8*)(Wob + idx) = hh;
        return;
    }
    const int bx  = blockIdx.x;
    const int bh  = bx / 15;
    const int qbm = bx % 15;
    const int qb  = SPLIT_Q0 + qbm;
    const int b   = bh >> 4;
    const int h   = bh & 15;

    const int slot0 = bh * SLOTS_BH + qbm * 2;
    const float* O0 = Scr + (size_t)slot0 * 4096;
    const float* O1 = O0 + 4096;
    const float* L0 = Scr + PO_FLOATS + (size_t)slot0 * 64;
    const float* L1 = L0 + 64;

    const int r  = threadIdx.x >> 2;
    const int cg = (threadIdx.x & 3) * 16;

    float inv = 1.0f / (L0[r] + L1[r]);

    u16x8 outv[2];
#pragma unroll
    for (int half = 0; half < 2; half++) {
        float4 a0 = *(const float4*)(O0 + r * 64 + cg + half * 8);
        float4 b0 = *(const float4*)(O0 + r * 64 + cg + half * 8 + 4);
        float4 a1 = *(const float4*)(O1 + r * 64 + cg + half * 8);
        float4 b1 = *(const float4*)(O1 + r * 64 + cg + half * 8 + 4);
        outv[half][0] = f2bfu((a0.x + a1.x) * inv);
        outv[half][1] = f2bfu((a0.y + a1.y) * inv);
        outv[half][2] = f2bfu((a0.z + a1.z) * inv);
        outv[half][3] = f2bfu((a0.w + a1.w) * inv);
        outv[half][4] = f2bfu((b0.x + b1.x) * inv);
        outv[half][5] = f2bfu((b0.y + b1.y) * inv);
        outv[half][6] = f2bfu((b0.z + b1.z) * inv);
        outv[half][7] = f2bfu((b0.w + b1.w) * inv);
    }
    const int s = qb * 64 + r;
    unsigned short* Ap = A + ((size_t)b * S_LEN + s) * DMODEL + h * DKH + cg;
    *(u16x8*)(Ap)     = outv[0];
    *(u16x8*)(Ap + 8) = outv[1];
}

extern "C" void kernel_launch(void* const* d_in, const int* in_sizes, int n_in,
                              void* d_out, int out_size, void* d_ws, size_t ws_size,
                              hipStream_t stream) {
    const float* x  = (const float*)d_in[0];
    const float* Wq = (const float*)d_in[1];
    const float* Wk = (const float*)d_in[2];
    const float* Wv = (const float*)d_in[3];
    const float* Wo = (const float*)d_in[4];
    float* out = (float*)d_out;

    unsigned short* Qw = (unsigned short*)d_ws;
    unsigned short* Kw = Qw + (size_t)MROWS * DMODEL;
    unsigned short* Vw = Kw + (size_t)MROWS * DMODEL;
    unsigned short* Wb = Vw + (size_t)MROWS * DMODEL;
    unsigned short* Aw = Wb;    // aliased; QKV completes before attn writes A
    unsigned short* Wob = Qw;   // aliased; Q dead after attn_mfma
    unsigned short* Xb = (unsigned short*)d_out;
    float* Scr = (float*)d_out;

    cvt_all<<<dim3(DMODEL * DMODEL / (256 * 8), 7), 256, 0, stream>>>(Wq, Wk, Wv, x, Wb, Xb);

    gemm_qkv<<<dim3(3 * DMODEL / 128, MROWS / 128), 256, 0, stream>>>(
        Xb, Wb, Qw, Kw, Vw);

    attn_mfma<<<dim3(NHEADS * BATCH, NPIECE), 128, 0, stream>>>(Qw, Kw, Vw, Aw, Scr);

    combine_cvtwo<<<dim3(480 + 512), 256, 0, stream>>>(Scr, Aw, Wo, Wob);

    gemm_wo<<<dim3(DMODEL / 128, MROWS / 64), 256, 0, stream>>>(Aw, Wob, out);
}